// Round 5
// baseline (342.845 us; speedup 1.0000x reference)
//
#include <hip/hip_runtime.h>
#include <hip/hip_bf16.h>
#include <cstdint>
#include <cstddef>

// Problem constants (reference: N=8192, C=512, H=8)
#define NN 8192
#define CC 512
#define HH 8

typedef __attribute__((ext_vector_type(8))) short short8;   // 8 bf16 = 4 VGPRs
typedef __attribute__((ext_vector_type(4))) float f32x4;

__device__ __forceinline__ void gload_lds16(const void* g, void* l) {
  __builtin_amdgcn_global_load_lds(
      (const __attribute__((address_space(1))) void*)g,
      (__attribute__((address_space(3))) void*)l, 16, 0, 0);
}

__device__ __forceinline__ f32x4 mfma16(short8 a, short8 b, f32x4 c) {
  return __builtin_amdgcn_mfma_f32_16x16x32_bf16(a, b, c, 0, 0, 0);
}

__device__ __forceinline__ float b2f(unsigned u) {  // low 16 bits = bf16
  union { unsigned i; float f; } x; x.i = u << 16; return x.f;
}

__device__ __forceinline__ void unpack8(uint4 v, float* f) {
  f[0] = b2f(v.x & 0xffffu); f[1] = b2f(v.x >> 16);
  f[2] = b2f(v.y & 0xffffu); f[3] = b2f(v.y >> 16);
  f[4] = b2f(v.z & 0xffffu); f[5] = b2f(v.z >> 16);
  f[6] = b2f(v.w & 0xffffu); f[7] = b2f(v.w >> 16);
}

// ---------------------------------------------------------------------------
// Split-precision projection GEMM: [Q|K] = x @ [W_theta|W_phi] via
// ah*bh + ah*bl + al*bh (Markidis). Output split into bf16 hi+lo pairs
// (= fp32 to 2^-17) for later exact recompute. 128x128 tile, 48 MFMA/barrier.
// ---------------------------------------------------------------------------
__global__ __launch_bounds__(256, 2) void gemm_qk(
    const __hip_bfloat16* __restrict__ ah, const __hip_bfloat16* __restrict__ al, int lda,
    const __hip_bfloat16* __restrict__ bh, const __hip_bfloat16* __restrict__ bl, int ldb,
    int K,
    __hip_bfloat16* __restrict__ outHi, __hip_bfloat16* __restrict__ outLo, int ldc,
    const float* __restrict__ biasCol)
{
  __shared__ __align__(16) char lds[32768];  // Ah | Al | Bh | Bl, 8KB each
  const int tid  = threadIdx.x;
  const int lane = tid & 63;
  const int wave = tid >> 6;
  const int bm = blockIdx.y, bn = blockIdx.x;
  const int wr = wave >> 1, wc = wave & 1;
  const int fr = lane & 15, fq = lane >> 4;

  f32x4 acc[4][4] = {};

  for (int kt = 0; kt < K; kt += 32) {
    __syncthreads();
#pragma unroll
    for (int tile = 0; tile < 4; ++tile) {
      const __hip_bfloat16* tp = (tile == 0) ? ah : (tile == 1) ? al
                               : (tile == 2) ? bh : bl;
      const int ld = (tile < 2) ? lda : ldb;
      const int tb = ((tile < 2) ? bm : bn) * 128;
#pragma unroll
      for (int half = 0; half < 2; ++half) {
        int sub = half * 256 + tid;
        int row = sub >> 2, ch = sub & 3;
        gload_lds16(tp + (size_t)(tb + row) * ld + kt + ch * 8,
                    lds + tile * 8192 + sub * 16);
      }
    }
    __syncthreads();

    short8 fah[4], fal[4], fbh[4], fbl[4];
#pragma unroll
    for (int i = 0; i < 4; ++i) {
      const int ra = (wr * 64 + i * 16 + fr) * 64 + fq * 16;
      const int rb = (wc * 64 + i * 16 + fr) * 64 + fq * 16;
      fah[i] = *(const short8*)(lds +         ra);
      fal[i] = *(const short8*)(lds +  8192 + ra);
      fbh[i] = *(const short8*)(lds + 16384 + rb);
      fbl[i] = *(const short8*)(lds + 24576 + rb);
    }
#pragma unroll
    for (int i = 0; i < 4; ++i)
#pragma unroll
      for (int j = 0; j < 4; ++j) {
        acc[i][j] = mfma16(fah[i], fbh[j], acc[i][j]);
        acc[i][j] = mfma16(fah[i], fbl[j], acc[i][j]);
        acc[i][j] = mfma16(fal[i], fbh[j], acc[i][j]);
      }
  }

  // C/D layout: col = lane&15, row = (lane>>4)*4 + t  [m89]
#pragma unroll
  for (int i = 0; i < 4; ++i)
#pragma unroll
    for (int j = 0; j < 4; ++j) {
      const int rbase = bm * 128 + wr * 64 + i * 16 + fq * 4;
      const int col   = bn * 128 + wc * 64 + j * 16 + fr;
#pragma unroll
      for (int t = 0; t < 4; ++t) {
        float v = acc[i][j][t] + biasCol[col];
        __hip_bfloat16 h = __float2bfloat16(v);
        outHi[(size_t)(rbase + t) * ldc + col] = h;
        outLo[(size_t)(rbase + t) * ldc + col] = __float2bfloat16(v - __bfloat162float(h));
      }
    }
}

// ---------------------------------------------------------------------------
// SIM GEMM — ROUND-16: fixes R15's race. The vmcnt gate for tile t now
// executes BEFORE any ds_read of tile t (R15 issued the reads first ->
// stale LDS). Structure per K-tile t (256x256 tile, BK=32, 8 waves,
// 96KB triple-buffered LDS, tile t -> buf t%3):
//   B0: vmcnt(4) [t=15: vmcnt(0)] ; s_barrier ; sched_barrier
//       -> all waves' tile-t chunks are in LDS; tile t+1 stays in flight.
//   phase 1: ds_read A rows 0..3 + B; stage chunk0(t+2) -> buf (t+2)%3;
//            lgkmcnt(0)+sched_barrier; setprio(1); 16 MFMA; setprio(0)
//   phase 2: ds_read A rows 4..7; stage chunk1(t+2);
//            lgkmcnt(0)+sched_barrier; setprio(1); 16 MFMA; setprio(0)
// ONE barrier per K-tile: within an inter-barrier window, reads touch
// buf t%3 only and writes touch buf (t+2)%3 only (disjoint); tile t-1's
// reads (in buf (t+2)%3) completed before each wave's lgkmcnt(0) in
// iter t-1, which precedes B0(t) for all waves -> WAR-safe.
// vmcnt queue (per-wave FIFO, in-order retire): top of iter t outstanding
// = {t:4, t+1:4}; vmcnt(4) retires exactly tile t's. Iter t stages 4
// loads (2+2) -> invariant holds. t=15: {15:4} -> vmcnt(0).
// Swizzle (byte ^= ((byte>>9)&1)<<5) on global source + read address,
// LDS dests linear — unchanged from R14 (bank conflicts measured 0).
// Epilogue and accumulation order identical to R14 (bit-identical output).
// ---------------------------------------------------------------------------
__global__ __launch_bounds__(512, 2) void gemm_sim(
    const __hip_bfloat16* __restrict__ A, int lda,
    const __hip_bfloat16* __restrict__ B, int ldb,
    int K,
    float* __restrict__ segMax, unsigned char* __restrict__ sim4)
{
  (void)K;  // fixed: 512 = 16 K-tiles of 32
  __shared__ __align__(16) char lds[98304];  // A: 3x16KB at 0 | B: 3x16KB at 49152
  const int tid  = threadIdx.x;              // 0..511
  const int lane = tid & 63;
  const int wave = tid >> 6;                 // 0..7
  const int bm = blockIdx.y, bn = blockIdx.x;
  const int wm = wave >> 2;                  // 0..1  (row half)
  const int wn = wave & 3;                   // 0..3  (col quarter = segment)
  const int fr = lane & 15, fq = lane >> 4;

  // ---- staging source offsets (global pre-swizzle; LDS dest stays linear) --
  // chunk c covers LDS dest bytes [c*8192 + tid*16, +16) of a 16KB tile buf.
  // source linear = dest ^ ((dest>>9)&1)<<5 ; row = s>>6, colel = (s&63)>>1.
  int s0 = tid * 16;          s0 ^= ((s0 >> 9) & 1) << 5;
  int s1 = 8192 + tid * 16;   s1 ^= ((s1 >> 9) & 1) << 5;
  const int off0 = (s0 >> 6) * 1024 + ((s0 & 63) >> 1);   // element offset
  const int off1 = (s1 >> 6) * 1024 + ((s1 & 63) >> 1);

  // ---- fragment read bases (swizzled); flip bit is per-thread constant ----
  const int fl = ((fr >> 3) & 1) << 5;
  const int baseAs = (((wm * 128 + fr) * 64) + fq * 16) ^ fl;   // within A buf
  const int baseBs = (((wn * 64 + fr) * 64) + fq * 16) ^ fl;    // within B buf

  const __hip_bfloat16* Ab = A + (size_t)bm * 256 * lda;
  const __hip_bfloat16* Bb = B + (size_t)bn * 256 * ldb;

  // chunk0 = LDS bytes [0,8192) of a tile buf, chunk1 = [8192,16384)
#define STAGE_C0(t, buf) do {                                                \
    const __hip_bfloat16* ap_ = Ab + (t) * 32;                               \
    const __hip_bfloat16* bp_ = Bb + (t) * 32;                               \
    gload_lds16(ap_ + off0, lds + (buf) * 16384 + tid * 16);                 \
    gload_lds16(bp_ + off0, lds + 49152 + (buf) * 16384 + tid * 16);         \
  } while (0)
#define STAGE_C1(t, buf) do {                                                \
    const __hip_bfloat16* ap_ = Ab + (t) * 32;                               \
    const __hip_bfloat16* bp_ = Bb + (t) * 32;                               \
    gload_lds16(ap_ + off1, lds + (buf) * 16384 + 8192 + tid * 16);          \
    gload_lds16(bp_ + off1, lds + 49152 + (buf) * 16384 + 8192 + tid * 16);  \
  } while (0)

  f32x4 acc[8][4] = {};

  // prologue: tiles 0 -> buf0, 1 -> buf1 (FIFO: [t0c0, t0c1, t1c0, t1c1])
  STAGE_C0(0, 0); STAGE_C1(0, 0);
  STAGE_C0(1, 1); STAGE_C1(1, 1);

#pragma unroll
  for (int t = 0; t < 16; ++t) {
    const int buf = t % 3;
    const int nbuf = (t + 2) % 3;
    const char* Abuf = lds + buf * 16384;
    const char* Bbuf = lds + 49152 + buf * 16384;

    // ===== B0: gate tile t for ALL waves, then one inter-barrier window =====
    if (t == 15) asm volatile("s_waitcnt vmcnt(0)" ::: "memory");
    else         asm volatile("s_waitcnt vmcnt(4)" ::: "memory");
    __builtin_amdgcn_s_barrier();
    __builtin_amdgcn_sched_barrier(0);

    // ===== phase 1: A rows 0..3 + all B; stage chunk0(t+2); MFMA rows 0..3
    short8 a[4], b4[4];
#pragma unroll
    for (int i = 0; i < 4; ++i)
      a[i] = *(const short8*)(Abuf + baseAs + i * 1024);
#pragma unroll
    for (int j = 0; j < 4; ++j)
      b4[j] = *(const short8*)(Bbuf + baseBs + j * 1024);
    if (t < 14) STAGE_C0(t + 2, nbuf);

    asm volatile("s_waitcnt lgkmcnt(0)" ::: "memory");
    __builtin_amdgcn_sched_barrier(0);
    __builtin_amdgcn_s_setprio(1);
#pragma unroll
    for (int i = 0; i < 4; ++i)
#pragma unroll
      for (int j = 0; j < 4; ++j)
        acc[i][j] = mfma16(a[i], b4[j], acc[i][j]);
    __builtin_amdgcn_s_setprio(0);

    // ===== phase 2: A rows 4..7 (B reused); stage chunk1(t+2); MFMA rows 4..7
    short8 a2[4];
#pragma unroll
    for (int i = 0; i < 4; ++i)
      a2[i] = *(const short8*)(Abuf + baseAs + (4 + i) * 1024);
    if (t < 14) STAGE_C1(t + 2, nbuf);

    asm volatile("s_waitcnt lgkmcnt(0)" ::: "memory");
    __builtin_amdgcn_sched_barrier(0);
    __builtin_amdgcn_s_setprio(1);
#pragma unroll
    for (int i = 0; i < 4; ++i)
#pragma unroll
      for (int j = 0; j < 4; ++j)
        acc[4 + i][j] = mfma16(a2[i], b4[j], acc[4 + i][j]);
    __builtin_amdgcn_s_setprio(0);
  }
#undef STAGE_C0
#undef STAGE_C1

  // ---- epilogue: segMax + deficit nibbles (same semantics as R12) ----
  const int seg = bn * 4 + wn;
#pragma unroll
  for (int i = 0; i < 8; ++i)
#pragma unroll
    for (int tt = 0; tt < 4; ++tt) {
      const int row = bm * 256 + wm * 128 + i * 16 + fq * 4 + tt;
      float mx = fmaxf(fmaxf(acc[i][0][tt], acc[i][1][tt]),
                       fmaxf(acc[i][2][tt], acc[i][3][tt]));
      mx = fmaxf(mx, __shfl_xor(mx, 1));
      mx = fmaxf(mx, __shfl_xor(mx, 2));
      mx = fmaxf(mx, __shfl_xor(mx, 4));
      mx = fmaxf(mx, __shfl_xor(mx, 8));
      if (fr == 0) segMax[(size_t)row * 128 + seg] = mx;
      unsigned q[4];
#pragma unroll
      for (int j = 0; j < 4; ++j)
        q[j] = (unsigned)fminf((mx - acc[i][j][tt]) * (4.0f / 3.0f), 15.0f);
      unsigned char* dst = sim4 + (size_t)row * (NN / 2) + seg * 32 + fr;
      dst[0]  = (unsigned char)(q[0] | (q[1] << 4));
      dst[16] = (unsigned char)(q[2] | (q[3] << 4));
    }
}

// ---------------------------------------------------------------------------
// Fused select + z-gather, one WAVE per row, barrier-free (R6 lesson).
// 1) M = max over the row's 128 segMax (wave reduce, no global state).
// 2) segs with segMax > M-11 (~2-3; tail DROPPED: mass <= ~15*e^-10.5 ~ 4e-4
//    relative — below threshold): load 32 sim4 bytes, s_approx = segv - 0.75q.
// 3) candidates s_approx > M-11: exact fp32 recompute from QK hi/lo;
//    keep p > M-10.5.
// 4) weights off exact max; z[n] = (sum w_i x[m_i]) / L, fp32 -> bf16.
// ---------------------------------------------------------------------------
__global__ __launch_bounds__(256) void select_zgather(
    const float* __restrict__ segMax, const unsigned char* __restrict__ sim4,
    const __hip_bfloat16* __restrict__ QKhi, const __hip_bfloat16* __restrict__ QKlo,
    const float* __restrict__ x,
    __hip_bfloat16* __restrict__ z)
{
  const int lane = threadIdx.x & 63;
  const int n = blockIdx.x * 4 + (threadIdx.x >> 6);

  float2 sm = ((const float2*)(segMax + (size_t)n * 128))[lane];
  float M = fmaxf(sm.x, sm.y);
#pragma unroll
  for (int off = 32; off; off >>= 1) M = fmaxf(M, __shfl_xor(M, off));

  const unsigned long long b0 = __ballot(sm.x > M - 11.0f);
  const unsigned long long b1 = __ballot(sm.y > M - 11.0f);

  // hoist q row (hi+lo reconstruct, 8 dims/lane)
  float qf[8];
  {
    uint4 qh4 = ((const uint4*)(QKhi + (size_t)n * 1024))[lane];
    uint4 ql4 = ((const uint4*)(QKlo + (size_t)n * 1024))[lane];
    float a[8], b[8];
    unpack8(qh4, a); unpack8(ql4, b);
#pragma unroll
    for (int e = 0; e < 8; ++e) qf[e] = a[e] + b[e];
  }

  const unsigned char* srow4 = sim4 + (size_t)n * (NN / 2);
  const int jj = lane >> 4;            // this lane's col-quarter within a seg
  const int shift = (jj & 1) * 4;
  const int boff = (jj >> 1) * 16 + (lane & 15);

  int nk = 0;
  float se_mine = -1e30f;
  int   mm_mine = 0;
#pragma unroll
  for (int half = 0; half < 2; ++half) {
    unsigned long long mask = half ? b1 : b0;
    while (mask) {
      const int b = __ffsll((unsigned long long)mask) - 1;
      mask &= mask - 1;
      const int seg = 2 * b + half;
      const float segv = __shfl(half ? sm.y : sm.x, b);
      const unsigned byte = srow4[seg * 32 + boff];
      const float sa = segv - 0.75f * (float)((byte >> shift) & 15u);
      unsigned long long cm = __ballot(sa > M - 11.0f);
      while (cm) {
        const int c = __ffsll((unsigned long long)cm) - 1;
        cm &= cm - 1;
        const int m = seg * 64 + c;
        uint4 kh4 = ((const uint4*)(QKhi + (size_t)m * 1024 + 512))[lane];
        uint4 kl4 = ((const uint4*)(QKlo + (size_t)m * 1024 + 512))[lane];
        float a[8], bb[8];
        unpack8(kh4, a); unpack8(kl4, bb);
        float p = 0.f;
#pragma unroll
        for (int e = 0; e < 8; ++e) p += qf[e] * (a[e] + bb[e]);
#pragma unroll
        for (int off = 32; off; off >>= 1) p += __shfl_xor(p, off);
        if (p > M - 10.5f) {
          if (lane == nk) { se_mine = p; mm_mine = m; }
          nk = (nk < 63) ? nk + 1 : nk;
        }
      }
    }
  }

  // exact max + normalizer (selected mass only; tail dropped)
  float Me = (lane < nk) ? se_mine : -1e30f;
#pragma unroll
  for (int off = 32; off; off >>= 1) Me = fmaxf(Me, __shfl_xor(Me, off));
  const float wv = __expf(se_mine - Me);      // valid only for lane < nk
  float Lr = (lane < nk) ? wv : 0.f;
#pragma unroll
  for (int off = 32; off; off >>= 1) Lr += __shfl_xor(Lr, off);

  // gather x rows (fp32, 2KB each, coalesced) into z
  float acc[8] = {};
  for (int i = 0; i < nk; ++i) {
    const int   m = __shfl(mm_mine, i);
    const float w = __shfl(wv, i);
    const float4* row = (const float4*)(x + (size_t)m * CC + 8 * lane);
    float4 a = row[0], b = row[1];
    acc[0] += w * a.x; acc[1] += w * a.y; acc[2] += w * a.z; acc[3] += w * a.w;
    acc[4] += w * b.x; acc[5] += w * b.y; acc[6] += w * b.z; acc[7] += w * b.w;
  }
  const float inv = 1.0f / Lr;
  short8 o;
#pragma unroll
  for (int e = 0; e < 8; ++e) {
    __hip_bfloat16 h = __float2bfloat16(acc[e] * inv);
    o[e] = *(short*)&h;
  }
  *(short8*)(z + (size_t)n * CC + 8 * lane) = o;
}

// ---------------------------------------------------------------------------
// gemm_zwk (R9 proven core): out[n][d] += 0.125 * sum_{h in group}
//   relu((z @ WkT^T)[n][h*512+d] + b_k[h][d])  via fire-and-forget atomicAdd.
// ---------------------------------------------------------------------------
__global__ __launch_bounds__(256, 2) void gemm_zwk(
    const __hip_bfloat16* __restrict__ z,
    const __hip_bfloat16* __restrict__ WkT,
    const float* __restrict__ bk,
    float* __restrict__ out)
{
  __shared__ __align__(16) char lds[16384];  // A 8KB | B 8KB
  const int tid  = threadIdx.x;
  const int lane = tid & 63;
  const int wave = tid >> 6;
  const int bn = blockIdx.x, bm = blockIdx.y, hg = blockIdx.z;
  const int wr = wave >> 1, wc = wave & 1;
  const int fr = lane & 15, fq = lane >> 4;

  f32x4 oacc[4][4] = {};

  for (int hh = 0; hh < 4; ++hh) {
    const int head = hg * 4 + hh;
    const __hip_bfloat16* B = WkT + (size_t)(head * 512 + bn * 128) * CC;
    f32x4 acc[4][4] = {};
    for (int kt = 0; kt < CC; kt += 32) {
      __syncthreads();
#pragma unroll
      for (int half = 0; half < 2; ++half) {
        int sub = half * 256 + tid;
        int row = sub >> 2, ch = sub & 3;
        gload_lds16(z + (size_t)(bm * 128 + row) * CC + kt + ch * 8, lds +        sub * 16);
        gload_lds16(B + (size_t)row * CC + kt + ch * 8,              lds + 8192 + sub * 16);
      }
      __syncthreads();

      short8 af[4], bf[4];
#pragma unroll
      for (int i = 0; i < 4; ++i) {
        af[i] = *(const short8*)(lds +        (wr * 64 + i * 16 + fr) * 64 + fq * 16);
        bf[i] = *(const short8*)(lds + 8192 + (wc * 64 + i * 16 + fr) * 64 + fq * 16);
      }
#pragma unroll
      for (int i = 0; i < 4; ++i)
#pragma unroll
        for (int j = 0; j < 4; ++j)
          acc[i][j] = mfma16(af[i], bf[j], acc[i][j]);
    }
#pragma unroll
    for (int j = 0; j < 4; ++j) {
      const int d = bn * 128 + wc * 64 + j * 16 + fr;
      const float bias = bk[head * CC + d];
#pragma unroll
      for (int i = 0; i < 4; ++i)
#pragma unroll
        for (int t = 0; t < 4; ++t)
          oacc[i][j][t] += fmaxf(acc[i][j][t] + bias, 0.f);
    }
  }

#pragma unroll
  for (int i = 0; i < 4; ++i)
#pragma unroll
    for (int j = 0; j < 4; ++j) {
      const int rbase = bm * 128 + wr * 64 + i * 16 + fq * 4;
      const int d     = bn * 128 + wc * 64 + j * 16 + fr;
#pragma unroll
      for (int t = 0; t < 4; ++t)
        atomicAdd(out + (size_t)(rbase + t) * CC + d, 0.125f * oacc[i][j][t]);
    }
}

// ---------------------------------------------------------------------------
// Merged prep (one launch, block-aligned ranges):
//   [0, 4194304)          x -> bf16 hi+lo split
//   [4194304, 4718592)    WT[j][c] = (j<512?Wth:Wph)[c][j&511], hi+lo
//   [4718592, 6815744)    WkT[j][c] = W_k[j>>9][c][j&511], bf16
//   [6815744, 6816768)    biasqk
//   [6816768, 7865344)    out zero-init (float4 per thread; atomics target)
// ---------------------------------------------------------------------------
__global__ void prep_all(const float* __restrict__ x,
                         const float* __restrict__ Wth, const float* __restrict__ Wph,
                         const float* __restrict__ bt, const float* __restrict__ bp,
                         const float* __restrict__ Wk,
                         __hip_bfloat16* __restrict__ xhi, __hip_bfloat16* __restrict__ xlo,
                         __hip_bfloat16* __restrict__ wthi, __hip_bfloat16* __restrict__ wtlo,
                         __hip_bfloat16* __restrict__ wkt, float* __restrict__ biasqk,
                         float* __restrict__ outz) {
  int idx = blockIdx.x * 256 + threadIdx.x;
  if (idx < 4194304) {
    float v = x[idx];
    __hip_bfloat16 h = __float2bfloat16(v);
    xhi[idx] = h;
    xlo[idx] = __float2bfloat16(v - __bfloat162float(h));
  } else if (idx < 4718592) {
    int i = idx - 4194304;
    int j = i >> 9, c = i & 511;
    const float* W = (j < 512) ? Wth : Wph;
    float v = W[(size_t)c * 512 + (j & 511)];
    __hip_bfloat16 h = __float2bfloat16(v);
    wthi[i] = h;
    wtlo[i] = __float2bfloat16(v - __bfloat162float(h));
  } else if (idx < 6815744) {
    int i = idx - 4718592;
    int j = i >> 9, c = i & 511;
    float v = Wk[(size_t)(j >> 9) * 262144 + (size_t)c * 512 + (j & 511)];
    wkt[i] = __float2bfloat16(v);
  } else if (idx < 6816768) {
    int i = idx - 6815744;
    biasqk[i] = (i < 512) ? bt[i] : bp[i - 512];
  } else if (idx < 7865344) {
    int i = idx - 6816768;
    ((float4*)outz)[i] = make_float4(0.f, 0.f, 0.f, 0.f);
  }
}

extern "C" void kernel_launch(void* const* d_in, const int* in_sizes, int n_in,
                              void* d_out, int out_size, void* d_ws, size_t ws_size,
                              hipStream_t stream) {
  const float* x  = (const float*)d_in[0];
  const float* Wt = (const float*)d_in[1];
  const float* bt = (const float*)d_in[2];
  const float* Wp = (const float*)d_in[3];
  const float* bp = (const float*)d_in[4];
  const float* Wk = (const float*)d_in[5];
  const float* bk = (const float*)d_in[6];
  float* out = (float*)d_out;

  // ---- workspace layout, peak ~100 MiB ----
  const size_t MB = 1024 * 1024;
  char* w = (char*)d_ws;
  __hip_bfloat16* xhi  = (__hip_bfloat16*)(w + 0 * MB);    // 8 MiB
  __hip_bfloat16* xlo  = (__hip_bfloat16*)(w + 8 * MB);    // 8 MiB
  __hip_bfloat16* WThi = (__hip_bfloat16*)(w + 16 * MB);   // 1 MiB
  __hip_bfloat16* WTlo = (__hip_bfloat16*)(w + 17 * MB);   // 1 MiB
  float*          biasqk = (float*)(w + 18 * MB);          // 4 KiB
  __hip_bfloat16* WkT  = (__hip_bfloat16*)(w + 20 * MB);   // 4 MiB
  __hip_bfloat16* QKhi = (__hip_bfloat16*)(w + 24 * MB);   // 16 MiB
  __hip_bfloat16* QKlo = (__hip_bfloat16*)(w + 40 * MB);   // 16 MiB
  __hip_bfloat16* z    = (__hip_bfloat16*)(w + 56 * MB);   // 8 MiB
  float*          segMax = (float*)(w + 64 * MB);          // 4 MiB
  unsigned char*  sim4   = (unsigned char*)(w + 68 * MB);  // 32 MiB

  // 1. prep + out zero-init (single launch)
  prep_all<<<7865344 / 256, 256, 0, stream>>>(x, Wt, Wp, bt, bp, Wk,
                                              xhi, xlo, WThi, WTlo, WkT, biasqk,
                                              out);

  // 2. [Q|K] projections, split precision, hi+lo outputs (8192 x 1024)
  gemm_qk<<<dim3(1024 / 128, NN / 128), 256, 0, stream>>>(
      xhi, xlo, CC, WThi, WTlo, CC, CC, QKhi, QKlo, 1024, biasqk);

  // 3. Q @ K^T -> segMax + deficit nibbles (256x256 tiles, gated pipeline)
  gemm_sim<<<dim3(NN / 256, NN / 256), 512, 0, stream>>>(
      QKhi, 1024, QKhi + 512, 1024, CC, segMax, sim4);

  // 4. fused select (nibble-filtered exact recompute) + z-gather
  select_zgather<<<NN / 4, 256, 0, stream>>>(segMax, sim4, QKhi, QKlo, x, z);

  // 5. out[n][d] += 0.125 * sum_{h in hg} relu(z @ W_k[h] + b_k[h])
  gemm_zwk<<<dim3(CC / 128, NN / 128, 2), 256, 0, stream>>>(z, WkT, bk, out);
}

// Round 6
// 315.097 us; speedup vs baseline: 1.0881x; 1.0881x over previous
//
#include <hip/hip_runtime.h>
#include <hip/hip_bf16.h>
#include <cstdint>
#include <cstddef>

// Problem constants (reference: N=8192, C=512, H=8)
#define NN 8192
#define CC 512
#define HH 8

typedef __attribute__((ext_vector_type(8))) short short8;   // 8 bf16 = 4 VGPRs
typedef __attribute__((ext_vector_type(4))) float f32x4;

__device__ __forceinline__ void gload_lds16(const void* g, void* l) {
  __builtin_amdgcn_global_load_lds(
      (const __attribute__((address_space(1))) void*)g,
      (__attribute__((address_space(3))) void*)l, 16, 0, 0);
}

__device__ __forceinline__ f32x4 mfma16(short8 a, short8 b, f32x4 c) {
  return __builtin_amdgcn_mfma_f32_16x16x32_bf16(a, b, c, 0, 0, 0);
}

__device__ __forceinline__ float b2f(unsigned u) {  // low 16 bits = bf16
  union { unsigned i; float f; } x; x.i = u << 16; return x.f;
}

__device__ __forceinline__ void unpack8(uint4 v, float* f) {
  f[0] = b2f(v.x & 0xffffu); f[1] = b2f(v.x >> 16);
  f[2] = b2f(v.y & 0xffffu); f[3] = b2f(v.y >> 16);
  f[4] = b2f(v.z & 0xffffu); f[5] = b2f(v.z >> 16);
  f[6] = b2f(v.w & 0xffffu); f[7] = b2f(v.w >> 16);
}

// ---------------------------------------------------------------------------
// Split-precision projection GEMM: [Q|K] = x @ [W_theta|W_phi] via
// ah*bh + ah*bl + al*bh (Markidis). Output split into bf16 hi+lo pairs
// (= fp32 to 2^-17) for later exact recompute. 128x128 tile, 48 MFMA/barrier.
// ---------------------------------------------------------------------------
__global__ __launch_bounds__(256, 2) void gemm_qk(
    const __hip_bfloat16* __restrict__ ah, const __hip_bfloat16* __restrict__ al, int lda,
    const __hip_bfloat16* __restrict__ bh, const __hip_bfloat16* __restrict__ bl, int ldb,
    int K,
    __hip_bfloat16* __restrict__ outHi, __hip_bfloat16* __restrict__ outLo, int ldc,
    const float* __restrict__ biasCol)
{
  __shared__ __align__(16) char lds[32768];  // Ah | Al | Bh | Bl, 8KB each
  const int tid  = threadIdx.x;
  const int lane = tid & 63;
  const int wave = tid >> 6;
  const int bm = blockIdx.y, bn = blockIdx.x;
  const int wr = wave >> 1, wc = wave & 1;
  const int fr = lane & 15, fq = lane >> 4;

  f32x4 acc[4][4] = {};

  for (int kt = 0; kt < K; kt += 32) {
    __syncthreads();
#pragma unroll
    for (int tile = 0; tile < 4; ++tile) {
      const __hip_bfloat16* tp = (tile == 0) ? ah : (tile == 1) ? al
                               : (tile == 2) ? bh : bl;
      const int ld = (tile < 2) ? lda : ldb;
      const int tb = ((tile < 2) ? bm : bn) * 128;
#pragma unroll
      for (int half = 0; half < 2; ++half) {
        int sub = half * 256 + tid;
        int row = sub >> 2, ch = sub & 3;
        gload_lds16(tp + (size_t)(tb + row) * ld + kt + ch * 8,
                    lds + tile * 8192 + sub * 16);
      }
    }
    __syncthreads();

    short8 fah[4], fal[4], fbh[4], fbl[4];
#pragma unroll
    for (int i = 0; i < 4; ++i) {
      const int ra = (wr * 64 + i * 16 + fr) * 64 + fq * 16;
      const int rb = (wc * 64 + i * 16 + fr) * 64 + fq * 16;
      fah[i] = *(const short8*)(lds +         ra);
      fal[i] = *(const short8*)(lds +  8192 + ra);
      fbh[i] = *(const short8*)(lds + 16384 + rb);
      fbl[i] = *(const short8*)(lds + 24576 + rb);
    }
#pragma unroll
    for (int i = 0; i < 4; ++i)
#pragma unroll
      for (int j = 0; j < 4; ++j) {
        acc[i][j] = mfma16(fah[i], fbh[j], acc[i][j]);
        acc[i][j] = mfma16(fah[i], fbl[j], acc[i][j]);
        acc[i][j] = mfma16(fal[i], fbh[j], acc[i][j]);
      }
  }

  // C/D layout: col = lane&15, row = (lane>>4)*4 + t  [m89]
#pragma unroll
  for (int i = 0; i < 4; ++i)
#pragma unroll
    for (int j = 0; j < 4; ++j) {
      const int rbase = bm * 128 + wr * 64 + i * 16 + fq * 4;
      const int col   = bn * 128 + wc * 64 + j * 16 + fr;
#pragma unroll
      for (int t = 0; t < 4; ++t) {
        float v = acc[i][j][t] + biasCol[col];
        __hip_bfloat16 h = __float2bfloat16(v);
        outHi[(size_t)(rbase + t) * ldc + col] = h;
        outLo[(size_t)(rbase + t) * ldc + col] = __float2bfloat16(v - __bfloat162float(h));
      }
    }
}

// ---------------------------------------------------------------------------
// SIM GEMM — ROUND-17: R16 gating, compiler-scheduled interior.
// R14/R16 both plateaued at MfmaUtil 33% despite different barrier/staging
// structures -> shared limiter was the manual lgkmcnt(0)+sched_barrier pins
// between ds_read bursts and MFMA clusters (rule #18 applies to ASM
// ds_reads; ours are compiler-visible loads with automatic fine-grained
// lgkmcnt). R17 removes the interior pins entirely: within each
// inter-barrier window the compiler interleaves {12 ds_reads, 4 stage
// loads, 32 MFMA} with per-consumer lgkmcnt(N).
//
// Safety proof (unchanged invariants):
//  - B0(t): vmcnt(4) [t=15: 0] + s_barrier + sched_barrier(0). The
//    sched_barrier is LOAD-BEARING: no instruction moves across the gate,
//    so no ds_read hoists above it and no MFMA sinks below the next one.
//  - Every ds_read of iter t feeds an MFMA issued in iter t; the compiler
//    inserts covering lgkmcnt before each consumer -> all reads retired
//    before the wave reaches B0(t+1). Hence staging into buf (t+2)%3
//    (holding tile t-1, read in iter t-1) is WAR-safe.
//  - vmcnt FIFO: top of iter t outstanding = {t:4, t+1:4} -> vmcnt(4)
//    retires tile t's. Iter t stages 4 loads -> invariant holds.
// Swizzle (byte ^= ((byte>>9)&1)<<5) on global source + read address,
// LDS dests linear — bank conflicts measured 0 (R14/R16).
// Accumulation order unchanged -> bit-identical output.
// ---------------------------------------------------------------------------
__global__ __launch_bounds__(512, 2) void gemm_sim(
    const __hip_bfloat16* __restrict__ A, int lda,
    const __hip_bfloat16* __restrict__ B, int ldb,
    int K,
    float* __restrict__ segMax, unsigned char* __restrict__ sim4)
{
  (void)K;  // fixed: 512 = 16 K-tiles of 32
  __shared__ __align__(16) char lds[98304];  // A: 3x16KB at 0 | B: 3x16KB at 49152
  const int tid  = threadIdx.x;              // 0..511
  const int lane = tid & 63;
  const int wave = tid >> 6;                 // 0..7
  const int bm = blockIdx.y, bn = blockIdx.x;
  const int wm = wave >> 2;                  // 0..1  (row half)
  const int wn = wave & 3;                   // 0..3  (col quarter = segment)
  const int fr = lane & 15, fq = lane >> 4;

  // ---- staging source offsets (global pre-swizzle; LDS dest stays linear) --
  int s0 = tid * 16;          s0 ^= ((s0 >> 9) & 1) << 5;
  int s1 = 8192 + tid * 16;   s1 ^= ((s1 >> 9) & 1) << 5;
  const int off0 = (s0 >> 6) * 1024 + ((s0 & 63) >> 1);   // element offset
  const int off1 = (s1 >> 6) * 1024 + ((s1 & 63) >> 1);

  // ---- fragment read bases (swizzled); flip bit is per-thread constant ----
  const int fl = ((fr >> 3) & 1) << 5;
  const int baseAs = (((wm * 128 + fr) * 64) + fq * 16) ^ fl;   // within A buf
  const int baseBs = (((wn * 64 + fr) * 64) + fq * 16) ^ fl;    // within B buf

  const __hip_bfloat16* Ab = A + (size_t)bm * 256 * lda;
  const __hip_bfloat16* Bb = B + (size_t)bn * 256 * ldb;

  // chunk0 = LDS bytes [0,8192) of a tile buf, chunk1 = [8192,16384)
#define STAGE_C0(t, buf) do {                                                \
    const __hip_bfloat16* ap_ = Ab + (t) * 32;                               \
    const __hip_bfloat16* bp_ = Bb + (t) * 32;                               \
    gload_lds16(ap_ + off0, lds + (buf) * 16384 + tid * 16);                 \
    gload_lds16(bp_ + off0, lds + 49152 + (buf) * 16384 + tid * 16);         \
  } while (0)
#define STAGE_C1(t, buf) do {                                                \
    const __hip_bfloat16* ap_ = Ab + (t) * 32;                               \
    const __hip_bfloat16* bp_ = Bb + (t) * 32;                               \
    gload_lds16(ap_ + off1, lds + (buf) * 16384 + 8192 + tid * 16);          \
    gload_lds16(bp_ + off1, lds + 49152 + (buf) * 16384 + 8192 + tid * 16);  \
  } while (0)

  f32x4 acc[8][4] = {};

  // prologue: tiles 0 -> buf0, 1 -> buf1 (FIFO: [t0c0, t0c1, t1c0, t1c1])
  STAGE_C0(0, 0); STAGE_C1(0, 0);
  STAGE_C0(1, 1); STAGE_C1(1, 1);

#pragma unroll
  for (int t = 0; t < 16; ++t) {
    const int buf = t % 3;
    const int nbuf = (t + 2) % 3;
    const char* Abuf = lds + buf * 16384;
    const char* Bbuf = lds + 49152 + buf * 16384;

    // ===== B0: gate tile t for ALL waves =====
    if (t == 15) asm volatile("s_waitcnt vmcnt(0)" ::: "memory");
    else         asm volatile("s_waitcnt vmcnt(4)" ::: "memory");
    __builtin_amdgcn_s_barrier();
    __builtin_amdgcn_sched_barrier(0);

    // ===== interior: compiler-scheduled reads + staging + 32 MFMA =====
    short8 a[8], b4[4];
#pragma unroll
    for (int i = 0; i < 4; ++i)
      a[i] = *(const short8*)(Abuf + baseAs + i * 1024);
#pragma unroll
    for (int j = 0; j < 4; ++j)
      b4[j] = *(const short8*)(Bbuf + baseBs + j * 1024);
    if (t < 14) STAGE_C0(t + 2, nbuf);

#pragma unroll
    for (int i = 0; i < 4; ++i)
#pragma unroll
      for (int j = 0; j < 4; ++j)
        acc[i][j] = mfma16(a[i], b4[j], acc[i][j]);

#pragma unroll
    for (int i = 0; i < 4; ++i)
      a[4 + i] = *(const short8*)(Abuf + baseAs + (4 + i) * 1024);
    if (t < 14) STAGE_C1(t + 2, nbuf);

#pragma unroll
    for (int i = 0; i < 4; ++i)
#pragma unroll
      for (int j = 0; j < 4; ++j)
        acc[4 + i][j] = mfma16(a[4 + i], b4[j], acc[4 + i][j]);
  }
#undef STAGE_C0
#undef STAGE_C1

  // ---- epilogue: segMax + deficit nibbles (same semantics as R12) ----
  const int seg = bn * 4 + wn;
#pragma unroll
  for (int i = 0; i < 8; ++i)
#pragma unroll
    for (int tt = 0; tt < 4; ++tt) {
      const int row = bm * 256 + wm * 128 + i * 16 + fq * 4 + tt;
      float mx = fmaxf(fmaxf(acc[i][0][tt], acc[i][1][tt]),
                       fmaxf(acc[i][2][tt], acc[i][3][tt]));
      mx = fmaxf(mx, __shfl_xor(mx, 1));
      mx = fmaxf(mx, __shfl_xor(mx, 2));
      mx = fmaxf(mx, __shfl_xor(mx, 4));
      mx = fmaxf(mx, __shfl_xor(mx, 8));
      if (fr == 0) segMax[(size_t)row * 128 + seg] = mx;
      unsigned q[4];
#pragma unroll
      for (int j = 0; j < 4; ++j)
        q[j] = (unsigned)fminf((mx - acc[i][j][tt]) * (4.0f / 3.0f), 15.0f);
      unsigned char* dst = sim4 + (size_t)row * (NN / 2) + seg * 32 + fr;
      dst[0]  = (unsigned char)(q[0] | (q[1] << 4));
      dst[16] = (unsigned char)(q[2] | (q[3] << 4));
    }
}

// ---------------------------------------------------------------------------
// Fused select + z-gather, one WAVE per row, barrier-free (R6 lesson).
// 1) M = max over the row's 128 segMax (wave reduce, no global state).
// 2) segs with segMax > M-11 (~2-3; tail DROPPED: mass <= ~15*e^-10.5 ~ 4e-4
//    relative — below threshold): load 32 sim4 bytes, s_approx = segv - 0.75q.
// 3) candidates s_approx > M-11: exact fp32 recompute from QK hi/lo;
//    keep p > M-10.5.
// 4) weights off exact max; z[n] = (sum w_i x[m_i]) / L, fp32 -> bf16.
// ---------------------------------------------------------------------------
__global__ __launch_bounds__(256) void select_zgather(
    const float* __restrict__ segMax, const unsigned char* __restrict__ sim4,
    const __hip_bfloat16* __restrict__ QKhi, const __hip_bfloat16* __restrict__ QKlo,
    const float* __restrict__ x,
    __hip_bfloat16* __restrict__ z)
{
  const int lane = threadIdx.x & 63;
  const int n = blockIdx.x * 4 + (threadIdx.x >> 6);

  float2 sm = ((const float2*)(segMax + (size_t)n * 128))[lane];
  float M = fmaxf(sm.x, sm.y);
#pragma unroll
  for (int off = 32; off; off >>= 1) M = fmaxf(M, __shfl_xor(M, off));

  const unsigned long long b0 = __ballot(sm.x > M - 11.0f);
  const unsigned long long b1 = __ballot(sm.y > M - 11.0f);

  // hoist q row (hi+lo reconstruct, 8 dims/lane)
  float qf[8];
  {
    uint4 qh4 = ((const uint4*)(QKhi + (size_t)n * 1024))[lane];
    uint4 ql4 = ((const uint4*)(QKlo + (size_t)n * 1024))[lane];
    float a[8], b[8];
    unpack8(qh4, a); unpack8(ql4, b);
#pragma unroll
    for (int e = 0; e < 8; ++e) qf[e] = a[e] + b[e];
  }

  const unsigned char* srow4 = sim4 + (size_t)n * (NN / 2);
  const int jj = lane >> 4;            // this lane's col-quarter within a seg
  const int shift = (jj & 1) * 4;
  const int boff = (jj >> 1) * 16 + (lane & 15);

  int nk = 0;
  float se_mine = -1e30f;
  int   mm_mine = 0;
#pragma unroll
  for (int half = 0; half < 2; ++half) {
    unsigned long long mask = half ? b1 : b0;
    while (mask) {
      const int b = __ffsll((unsigned long long)mask) - 1;
      mask &= mask - 1;
      const int seg = 2 * b + half;
      const float segv = __shfl(half ? sm.y : sm.x, b);
      const unsigned byte = srow4[seg * 32 + boff];
      const float sa = segv - 0.75f * (float)((byte >> shift) & 15u);
      unsigned long long cm = __ballot(sa > M - 11.0f);
      while (cm) {
        const int c = __ffsll((unsigned long long)cm) - 1;
        cm &= cm - 1;
        const int m = seg * 64 + c;
        uint4 kh4 = ((const uint4*)(QKhi + (size_t)m * 1024 + 512))[lane];
        uint4 kl4 = ((const uint4*)(QKlo + (size_t)m * 1024 + 512))[lane];
        float a[8], bb[8];
        unpack8(kh4, a); unpack8(kl4, bb);
        float p = 0.f;
#pragma unroll
        for (int e = 0; e < 8; ++e) p += qf[e] * (a[e] + bb[e]);
#pragma unroll
        for (int off = 32; off; off >>= 1) p += __shfl_xor(p, off);
        if (p > M - 10.5f) {
          if (lane == nk) { se_mine = p; mm_mine = m; }
          nk = (nk < 63) ? nk + 1 : nk;
        }
      }
    }
  }

  // exact max + normalizer (selected mass only; tail dropped)
  float Me = (lane < nk) ? se_mine : -1e30f;
#pragma unroll
  for (int off = 32; off; off >>= 1) Me = fmaxf(Me, __shfl_xor(Me, off));
  const float wv = __expf(se_mine - Me);      // valid only for lane < nk
  float Lr = (lane < nk) ? wv : 0.f;
#pragma unroll
  for (int off = 32; off; off >>= 1) Lr += __shfl_xor(Lr, off);

  // gather x rows (fp32, 2KB each, coalesced) into z
  float acc[8] = {};
  for (int i = 0; i < nk; ++i) {
    const int   m = __shfl(mm_mine, i);
    const float w = __shfl(wv, i);
    const float4* row = (const float4*)(x + (size_t)m * CC + 8 * lane);
    float4 a = row[0], b = row[1];
    acc[0] += w * a.x; acc[1] += w * a.y; acc[2] += w * a.z; acc[3] += w * a.w;
    acc[4] += w * b.x; acc[5] += w * b.y; acc[6] += w * b.z; acc[7] += w * b.w;
  }
  const float inv = 1.0f / Lr;
  short8 o;
#pragma unroll
  for (int e = 0; e < 8; ++e) {
    __hip_bfloat16 h = __float2bfloat16(acc[e] * inv);
    o[e] = *(short*)&h;
  }
  *(short8*)(z + (size_t)n * CC + 8 * lane) = o;
}

// ---------------------------------------------------------------------------
// gemm_zwk (R9 proven core): out[n][d] += 0.125 * sum_{h in group}
//   relu((z @ WkT^T)[n][h*512+d] + b_k[h][d])  via fire-and-forget atomicAdd.
// ---------------------------------------------------------------------------
__global__ __launch_bounds__(256, 2) void gemm_zwk(
    const __hip_bfloat16* __restrict__ z,
    const __hip_bfloat16* __restrict__ WkT,
    const float* __restrict__ bk,
    float* __restrict__ out)
{
  __shared__ __align__(16) char lds[16384];  // A 8KB | B 8KB
  const int tid  = threadIdx.x;
  const int lane = tid & 63;
  const int wave = tid >> 6;
  const int bn = blockIdx.x, bm = blockIdx.y, hg = blockIdx.z;
  const int wr = wave >> 1, wc = wave & 1;
  const int fr = lane & 15, fq = lane >> 4;

  f32x4 oacc[4][4] = {};

  for (int hh = 0; hh < 4; ++hh) {
    const int head = hg * 4 + hh;
    const __hip_bfloat16* B = WkT + (size_t)(head * 512 + bn * 128) * CC;
    f32x4 acc[4][4] = {};
    for (int kt = 0; kt < CC; kt += 32) {
      __syncthreads();
#pragma unroll
      for (int half = 0; half < 2; ++half) {
        int sub = half * 256 + tid;
        int row = sub >> 2, ch = sub & 3;
        gload_lds16(z + (size_t)(bm * 128 + row) * CC + kt + ch * 8, lds +        sub * 16);
        gload_lds16(B + (size_t)row * CC + kt + ch * 8,              lds + 8192 + sub * 16);
      }
      __syncthreads();

      short8 af[4], bf[4];
#pragma unroll
      for (int i = 0; i < 4; ++i) {
        af[i] = *(const short8*)(lds +        (wr * 64 + i * 16 + fr) * 64 + fq * 16);
        bf[i] = *(const short8*)(lds + 8192 + (wc * 64 + i * 16 + fr) * 64 + fq * 16);
      }
#pragma unroll
      for (int i = 0; i < 4; ++i)
#pragma unroll
        for (int j = 0; j < 4; ++j)
          acc[i][j] = mfma16(af[i], bf[j], acc[i][j]);
    }
#pragma unroll
    for (int j = 0; j < 4; ++j) {
      const int d = bn * 128 + wc * 64 + j * 16 + fr;
      const float bias = bk[head * CC + d];
#pragma unroll
      for (int i = 0; i < 4; ++i)
#pragma unroll
        for (int t = 0; t < 4; ++t)
          oacc[i][j][t] += fmaxf(acc[i][j][t] + bias, 0.f);
    }
  }

#pragma unroll
  for (int i = 0; i < 4; ++i)
#pragma unroll
    for (int j = 0; j < 4; ++j) {
      const int rbase = bm * 128 + wr * 64 + i * 16 + fq * 4;
      const int d     = bn * 128 + wc * 64 + j * 16 + fr;
#pragma unroll
      for (int t = 0; t < 4; ++t)
        atomicAdd(out + (size_t)(rbase + t) * CC + d, 0.125f * oacc[i][j][t]);
    }
}

// ---------------------------------------------------------------------------
// Merged prep (one launch, block-aligned ranges):
//   [0, 4194304)          x -> bf16 hi+lo split
//   [4194304, 4718592)    WT[j][c] = (j<512?Wth:Wph)[c][j&511], hi+lo
//   [4718592, 6815744)    WkT[j][c] = W_k[j>>9][c][j&511], bf16
//   [6815744, 6816768)    biasqk
//   [6816768, 7865344)    out zero-init (float4 per thread; atomics target)
// ---------------------------------------------------------------------------
__global__ void prep_all(const float* __restrict__ x,
                         const float* __restrict__ Wth, const float* __restrict__ Wph,
                         const float* __restrict__ bt, const float* __restrict__ bp,
                         const float* __restrict__ Wk,
                         __hip_bfloat16* __restrict__ xhi, __hip_bfloat16* __restrict__ xlo,
                         __hip_bfloat16* __restrict__ wthi, __hip_bfloat16* __restrict__ wtlo,
                         __hip_bfloat16* __restrict__ wkt, float* __restrict__ biasqk,
                         float* __restrict__ outz) {
  int idx = blockIdx.x * 256 + threadIdx.x;
  if (idx < 4194304) {
    float v = x[idx];
    __hip_bfloat16 h = __float2bfloat16(v);
    xhi[idx] = h;
    xlo[idx] = __float2bfloat16(v - __bfloat162float(h));
  } else if (idx < 4718592) {
    int i = idx - 4194304;
    int j = i >> 9, c = i & 511;
    const float* W = (j < 512) ? Wth : Wph;
    float v = W[(size_t)c * 512 + (j & 511)];
    __hip_bfloat16 h = __float2bfloat16(v);
    wthi[i] = h;
    wtlo[i] = __float2bfloat16(v - __bfloat162float(h));
  } else if (idx < 6815744) {
    int i = idx - 4718592;
    int j = i >> 9, c = i & 511;
    float v = Wk[(size_t)(j >> 9) * 262144 + (size_t)c * 512 + (j & 511)];
    wkt[i] = __float2bfloat16(v);
  } else if (idx < 6816768) {
    int i = idx - 6815744;
    biasqk[i] = (i < 512) ? bt[i] : bp[i - 512];
  } else if (idx < 7865344) {
    int i = idx - 6816768;
    ((float4*)outz)[i] = make_float4(0.f, 0.f, 0.f, 0.f);
  }
}

extern "C" void kernel_launch(void* const* d_in, const int* in_sizes, int n_in,
                              void* d_out, int out_size, void* d_ws, size_t ws_size,
                              hipStream_t stream) {
  const float* x  = (const float*)d_in[0];
  const float* Wt = (const float*)d_in[1];
  const float* bt = (const float*)d_in[2];
  const float* Wp = (const float*)d_in[3];
  const float* bp = (const float*)d_in[4];
  const float* Wk = (const float*)d_in[5];
  const float* bk = (const float*)d_in[6];
  float* out = (float*)d_out;

  // ---- workspace layout, peak ~100 MiB ----
  const size_t MB = 1024 * 1024;
  char* w = (char*)d_ws;
  __hip_bfloat16* xhi  = (__hip_bfloat16*)(w + 0 * MB);    // 8 MiB
  __hip_bfloat16* xlo  = (__hip_bfloat16*)(w + 8 * MB);    // 8 MiB
  __hip_bfloat16* WThi = (__hip_bfloat16*)(w + 16 * MB);   // 1 MiB
  __hip_bfloat16* WTlo = (__hip_bfloat16*)(w + 17 * MB);   // 1 MiB
  float*          biasqk = (float*)(w + 18 * MB);          // 4 KiB
  __hip_bfloat16* WkT  = (__hip_bfloat16*)(w + 20 * MB);   // 4 MiB
  __hip_bfloat16* QKhi = (__hip_bfloat16*)(w + 24 * MB);   // 16 MiB
  __hip_bfloat16* QKlo = (__hip_bfloat16*)(w + 40 * MB);   // 16 MiB
  __hip_bfloat16* z    = (__hip_bfloat16*)(w + 56 * MB);   // 8 MiB
  float*          segMax = (float*)(w + 64 * MB);          // 4 MiB
  unsigned char*  sim4   = (unsigned char*)(w + 68 * MB);  // 32 MiB

  // 1. prep + out zero-init (single launch)
  prep_all<<<7865344 / 256, 256, 0, stream>>>(x, Wt, Wp, bt, bp, Wk,
                                              xhi, xlo, WThi, WTlo, WkT, biasqk,
                                              out);

  // 2. [Q|K] projections, split precision, hi+lo outputs (8192 x 1024)
  gemm_qk<<<dim3(1024 / 128, NN / 128), 256, 0, stream>>>(
      xhi, xlo, CC, WThi, WTlo, CC, CC, QKhi, QKlo, 1024, biasqk);

  // 3. Q @ K^T -> segMax + deficit nibbles (256x256, compiler-scheduled)
  gemm_sim<<<dim3(NN / 256, NN / 256), 512, 0, stream>>>(
      QKhi, 1024, QKhi + 512, 1024, CC, segMax, sim4);

  // 4. fused select (nibble-filtered exact recompute) + z-gather
  select_zgather<<<NN / 4, 256, 0, stream>>>(segMax, sim4, QKhi, QKlo, x, z);

  // 5. out[n][d] += 0.125 * sum_{h in hg} relu(z @ W_k[h] + b_k[h])
  gemm_zwk<<<dim3(CC / 128, NN / 128, 2), 256, 0, stream>>>(z, WkT, bk, out);
}

// Round 7
// 314.520 us; speedup vs baseline: 1.0901x; 1.0018x over previous
//
#include <hip/hip_runtime.h>
#include <hip/hip_bf16.h>
#include <cstdint>
#include <cstddef>

// Problem constants (reference: N=8192, C=512, H=8)
#define NN 8192
#define CC 512
#define HH 8

typedef __attribute__((ext_vector_type(8))) short short8;   // 8 bf16 = 4 VGPRs
typedef __attribute__((ext_vector_type(4))) float f32x4;

__device__ __forceinline__ void gload_lds16(const void* g, void* l) {
  __builtin_amdgcn_global_load_lds(
      (const __attribute__((address_space(1))) void*)g,
      (__attribute__((address_space(3))) void*)l, 16, 0, 0);
}

__device__ __forceinline__ f32x4 mfma16(short8 a, short8 b, f32x4 c) {
  return __builtin_amdgcn_mfma_f32_16x16x32_bf16(a, b, c, 0, 0, 0);
}

__device__ __forceinline__ float b2f(unsigned u) {  // low 16 bits = bf16
  union { unsigned i; float f; } x; x.i = u << 16; return x.f;
}

__device__ __forceinline__ void unpack8(uint4 v, float* f) {
  f[0] = b2f(v.x & 0xffffu); f[1] = b2f(v.x >> 16);
  f[2] = b2f(v.y & 0xffffu); f[3] = b2f(v.y >> 16);
  f[4] = b2f(v.z & 0xffffu); f[5] = b2f(v.z >> 16);
  f[6] = b2f(v.w & 0xffffu); f[7] = b2f(v.w >> 16);
}

// ---------------------------------------------------------------------------
// Split-precision projection GEMM: [Q|K] = x @ [W_theta|W_phi] via
// ah*bh + ah*bl + al*bh (Markidis). Output split into bf16 hi+lo pairs
// (= fp32 to 2^-17) for later exact recompute. 128x128 tile, 48 MFMA/barrier.
// ---------------------------------------------------------------------------
__global__ __launch_bounds__(256, 2) void gemm_qk(
    const __hip_bfloat16* __restrict__ ah, const __hip_bfloat16* __restrict__ al, int lda,
    const __hip_bfloat16* __restrict__ bh, const __hip_bfloat16* __restrict__ bl, int ldb,
    int K,
    __hip_bfloat16* __restrict__ outHi, __hip_bfloat16* __restrict__ outLo, int ldc,
    const float* __restrict__ biasCol)
{
  __shared__ __align__(16) char lds[32768];  // Ah | Al | Bh | Bl, 8KB each
  const int tid  = threadIdx.x;
  const int lane = tid & 63;
  const int wave = tid >> 6;
  const int bm = blockIdx.y, bn = blockIdx.x;
  const int wr = wave >> 1, wc = wave & 1;
  const int fr = lane & 15, fq = lane >> 4;

  f32x4 acc[4][4] = {};

  for (int kt = 0; kt < K; kt += 32) {
    __syncthreads();
#pragma unroll
    for (int tile = 0; tile < 4; ++tile) {
      const __hip_bfloat16* tp = (tile == 0) ? ah : (tile == 1) ? al
                               : (tile == 2) ? bh : bl;
      const int ld = (tile < 2) ? lda : ldb;
      const int tb = ((tile < 2) ? bm : bn) * 128;
#pragma unroll
      for (int half = 0; half < 2; ++half) {
        int sub = half * 256 + tid;
        int row = sub >> 2, ch = sub & 3;
        gload_lds16(tp + (size_t)(tb + row) * ld + kt + ch * 8,
                    lds + tile * 8192 + sub * 16);
      }
    }
    __syncthreads();

    short8 fah[4], fal[4], fbh[4], fbl[4];
#pragma unroll
    for (int i = 0; i < 4; ++i) {
      const int ra = (wr * 64 + i * 16 + fr) * 64 + fq * 16;
      const int rb = (wc * 64 + i * 16 + fr) * 64 + fq * 16;
      fah[i] = *(const short8*)(lds +         ra);
      fal[i] = *(const short8*)(lds +  8192 + ra);
      fbh[i] = *(const short8*)(lds + 16384 + rb);
      fbl[i] = *(const short8*)(lds + 24576 + rb);
    }
#pragma unroll
    for (int i = 0; i < 4; ++i)
#pragma unroll
      for (int j = 0; j < 4; ++j) {
        acc[i][j] = mfma16(fah[i], fbh[j], acc[i][j]);
        acc[i][j] = mfma16(fah[i], fbl[j], acc[i][j]);
        acc[i][j] = mfma16(fal[i], fbh[j], acc[i][j]);
      }
  }

  // C/D layout: col = lane&15, row = (lane>>4)*4 + t  [m89]
#pragma unroll
  for (int i = 0; i < 4; ++i)
#pragma unroll
    for (int j = 0; j < 4; ++j) {
      const int rbase = bm * 128 + wr * 64 + i * 16 + fq * 4;
      const int col   = bn * 128 + wc * 64 + j * 16 + fr;
#pragma unroll
      for (int t = 0; t < 4; ++t) {
        float v = acc[i][j][t] + biasCol[col];
        __hip_bfloat16 h = __float2bfloat16(v);
        outHi[(size_t)(rbase + t) * ldc + col] = h;
        outLo[(size_t)(rbase + t) * ldc + col] = __float2bfloat16(v - __bfloat162float(h));
      }
    }
}

// ---------------------------------------------------------------------------
// SIM GEMM — R17 (frozen): vmcnt-gated triple-buffer, compiler-scheduled
// interior, XOR swizzle. 84 us, MfmaUtil 36%, bank conflicts 0.
// ---------------------------------------------------------------------------
__global__ __launch_bounds__(512, 2) void gemm_sim(
    const __hip_bfloat16* __restrict__ A, int lda,
    const __hip_bfloat16* __restrict__ B, int ldb,
    int K,
    float* __restrict__ segMax, unsigned char* __restrict__ sim4)
{
  (void)K;  // fixed: 512 = 16 K-tiles of 32
  __shared__ __align__(16) char lds[98304];  // A: 3x16KB at 0 | B: 3x16KB at 49152
  const int tid  = threadIdx.x;              // 0..511
  const int lane = tid & 63;
  const int wave = tid >> 6;                 // 0..7
  const int bm = blockIdx.y, bn = blockIdx.x;
  const int wm = wave >> 2;                  // 0..1  (row half)
  const int wn = wave & 3;                   // 0..3  (col quarter = segment)
  const int fr = lane & 15, fq = lane >> 4;

  // ---- staging source offsets (global pre-swizzle; LDS dest stays linear) --
  int s0 = tid * 16;          s0 ^= ((s0 >> 9) & 1) << 5;
  int s1 = 8192 + tid * 16;   s1 ^= ((s1 >> 9) & 1) << 5;
  const int off0 = (s0 >> 6) * 1024 + ((s0 & 63) >> 1);   // element offset
  const int off1 = (s1 >> 6) * 1024 + ((s1 & 63) >> 1);

  // ---- fragment read bases (swizzled); flip bit is per-thread constant ----
  const int fl = ((fr >> 3) & 1) << 5;
  const int baseAs = (((wm * 128 + fr) * 64) + fq * 16) ^ fl;   // within A buf
  const int baseBs = (((wn * 64 + fr) * 64) + fq * 16) ^ fl;    // within B buf

  const __hip_bfloat16* Ab = A + (size_t)bm * 256 * lda;
  const __hip_bfloat16* Bb = B + (size_t)bn * 256 * ldb;

  // chunk0 = LDS bytes [0,8192) of a tile buf, chunk1 = [8192,16384)
#define STAGE_C0(t, buf) do {                                                \
    const __hip_bfloat16* ap_ = Ab + (t) * 32;                               \
    const __hip_bfloat16* bp_ = Bb + (t) * 32;                               \
    gload_lds16(ap_ + off0, lds + (buf) * 16384 + tid * 16);                 \
    gload_lds16(bp_ + off0, lds + 49152 + (buf) * 16384 + tid * 16);         \
  } while (0)
#define STAGE_C1(t, buf) do {                                                \
    const __hip_bfloat16* ap_ = Ab + (t) * 32;                               \
    const __hip_bfloat16* bp_ = Bb + (t) * 32;                               \
    gload_lds16(ap_ + off1, lds + (buf) * 16384 + 8192 + tid * 16);          \
    gload_lds16(bp_ + off1, lds + 49152 + (buf) * 16384 + 8192 + tid * 16);  \
  } while (0)

  f32x4 acc[8][4] = {};

  // prologue: tiles 0 -> buf0, 1 -> buf1 (FIFO: [t0c0, t0c1, t1c0, t1c1])
  STAGE_C0(0, 0); STAGE_C1(0, 0);
  STAGE_C0(1, 1); STAGE_C1(1, 1);

#pragma unroll
  for (int t = 0; t < 16; ++t) {
    const int buf = t % 3;
    const int nbuf = (t + 2) % 3;
    const char* Abuf = lds + buf * 16384;
    const char* Bbuf = lds + 49152 + buf * 16384;

    // ===== B0: gate tile t for ALL waves =====
    if (t == 15) asm volatile("s_waitcnt vmcnt(0)" ::: "memory");
    else         asm volatile("s_waitcnt vmcnt(4)" ::: "memory");
    __builtin_amdgcn_s_barrier();
    __builtin_amdgcn_sched_barrier(0);

    // ===== interior: compiler-scheduled reads + staging + 32 MFMA =====
    short8 a[8], b4[4];
#pragma unroll
    for (int i = 0; i < 4; ++i)
      a[i] = *(const short8*)(Abuf + baseAs + i * 1024);
#pragma unroll
    for (int j = 0; j < 4; ++j)
      b4[j] = *(const short8*)(Bbuf + baseBs + j * 1024);
    if (t < 14) STAGE_C0(t + 2, nbuf);

#pragma unroll
    for (int i = 0; i < 4; ++i)
#pragma unroll
      for (int j = 0; j < 4; ++j)
        acc[i][j] = mfma16(a[i], b4[j], acc[i][j]);

#pragma unroll
    for (int i = 0; i < 4; ++i)
      a[4 + i] = *(const short8*)(Abuf + baseAs + (4 + i) * 1024);
    if (t < 14) STAGE_C1(t + 2, nbuf);

#pragma unroll
    for (int i = 0; i < 4; ++i)
#pragma unroll
      for (int j = 0; j < 4; ++j)
        acc[4 + i][j] = mfma16(a[4 + i], b4[j], acc[4 + i][j]);
  }
#undef STAGE_C0
#undef STAGE_C1

  // ---- epilogue: segMax + deficit nibbles (same semantics as R12) ----
  const int seg = bn * 4 + wn;
#pragma unroll
  for (int i = 0; i < 8; ++i)
#pragma unroll
    for (int tt = 0; tt < 4; ++tt) {
      const int row = bm * 256 + wm * 128 + i * 16 + fq * 4 + tt;
      float mx = fmaxf(fmaxf(acc[i][0][tt], acc[i][1][tt]),
                       fmaxf(acc[i][2][tt], acc[i][3][tt]));
      mx = fmaxf(mx, __shfl_xor(mx, 1));
      mx = fmaxf(mx, __shfl_xor(mx, 2));
      mx = fmaxf(mx, __shfl_xor(mx, 4));
      mx = fmaxf(mx, __shfl_xor(mx, 8));
      if (fr == 0) segMax[(size_t)row * 128 + seg] = mx;
      unsigned q[4];
#pragma unroll
      for (int j = 0; j < 4; ++j)
        q[j] = (unsigned)fminf((mx - acc[i][j][tt]) * (4.0f / 3.0f), 15.0f);
      unsigned char* dst = sim4 + (size_t)row * (NN / 2) + seg * 32 + fr;
      dst[0]  = (unsigned char)(q[0] | (q[1] << 4));
      dst[16] = (unsigned char)(q[2] | (q[3] << 4));
    }
}

// ---------------------------------------------------------------------------
// Fused select + z-gather, one WAVE per row, barrier-free (R6 lesson).
// ---------------------------------------------------------------------------
__global__ __launch_bounds__(256) void select_zgather(
    const float* __restrict__ segMax, const unsigned char* __restrict__ sim4,
    const __hip_bfloat16* __restrict__ QKhi, const __hip_bfloat16* __restrict__ QKlo,
    const float* __restrict__ x,
    __hip_bfloat16* __restrict__ z)
{
  const int lane = threadIdx.x & 63;
  const int n = blockIdx.x * 4 + (threadIdx.x >> 6);

  float2 sm = ((const float2*)(segMax + (size_t)n * 128))[lane];
  float M = fmaxf(sm.x, sm.y);
#pragma unroll
  for (int off = 32; off; off >>= 1) M = fmaxf(M, __shfl_xor(M, off));

  const unsigned long long b0 = __ballot(sm.x > M - 11.0f);
  const unsigned long long b1 = __ballot(sm.y > M - 11.0f);

  // hoist q row (hi+lo reconstruct, 8 dims/lane)
  float qf[8];
  {
    uint4 qh4 = ((const uint4*)(QKhi + (size_t)n * 1024))[lane];
    uint4 ql4 = ((const uint4*)(QKlo + (size_t)n * 1024))[lane];
    float a[8], b[8];
    unpack8(qh4, a); unpack8(ql4, b);
#pragma unroll
    for (int e = 0; e < 8; ++e) qf[e] = a[e] + b[e];
  }

  const unsigned char* srow4 = sim4 + (size_t)n * (NN / 2);
  const int jj = lane >> 4;            // this lane's col-quarter within a seg
  const int shift = (jj & 1) * 4;
  const int boff = (jj >> 1) * 16 + (lane & 15);

  int nk = 0;
  float se_mine = -1e30f;
  int   mm_mine = 0;
#pragma unroll
  for (int half = 0; half < 2; ++half) {
    unsigned long long mask = half ? b1 : b0;
    while (mask) {
      const int b = __ffsll((unsigned long long)mask) - 1;
      mask &= mask - 1;
      const int seg = 2 * b + half;
      const float segv = __shfl(half ? sm.y : sm.x, b);
      const unsigned byte = srow4[seg * 32 + boff];
      const float sa = segv - 0.75f * (float)((byte >> shift) & 15u);
      unsigned long long cm = __ballot(sa > M - 11.0f);
      while (cm) {
        const int c = __ffsll((unsigned long long)cm) - 1;
        cm &= cm - 1;
        const int m = seg * 64 + c;
        uint4 kh4 = ((const uint4*)(QKhi + (size_t)m * 1024 + 512))[lane];
        uint4 kl4 = ((const uint4*)(QKlo + (size_t)m * 1024 + 512))[lane];
        float a[8], bb[8];
        unpack8(kh4, a); unpack8(kl4, bb);
        float p = 0.f;
#pragma unroll
        for (int e = 0; e < 8; ++e) p += qf[e] * (a[e] + bb[e]);
#pragma unroll
        for (int off = 32; off; off >>= 1) p += __shfl_xor(p, off);
        if (p > M - 10.5f) {
          if (lane == nk) { se_mine = p; mm_mine = m; }
          nk = (nk < 63) ? nk + 1 : nk;
        }
      }
    }
  }

  // exact max + normalizer (selected mass only; tail dropped)
  float Me = (lane < nk) ? se_mine : -1e30f;
#pragma unroll
  for (int off = 32; off; off >>= 1) Me = fmaxf(Me, __shfl_xor(Me, off));
  const float wv = __expf(se_mine - Me);      // valid only for lane < nk
  float Lr = (lane < nk) ? wv : 0.f;
#pragma unroll
  for (int off = 32; off; off >>= 1) Lr += __shfl_xor(Lr, off);

  // gather x rows (fp32, 2KB each, coalesced) into z
  float acc[8] = {};
  for (int i = 0; i < nk; ++i) {
    const int   m = __shfl(mm_mine, i);
    const float w = __shfl(wv, i);
    const float4* row = (const float4*)(x + (size_t)m * CC + 8 * lane);
    float4 a = row[0], b = row[1];
    acc[0] += w * a.x; acc[1] += w * a.y; acc[2] += w * a.z; acc[3] += w * a.w;
    acc[4] += w * b.x; acc[5] += w * b.y; acc[6] += w * b.z; acc[7] += w * b.w;
  }
  const float inv = 1.0f / Lr;
  short8 o;
#pragma unroll
  for (int e = 0; e < 8; ++e) {
    __hip_bfloat16 h = __float2bfloat16(acc[e] * inv);
    o[e] = *(short*)&h;
  }
  *(short8*)(z + (size_t)n * CC + 8 * lane) = o;
}

// ---------------------------------------------------------------------------
// gemm_zwk — ROUND-18: R17 structure ported. Flat 64-virtual-tile loop
// (head = vt>>4, kt = (vt&15)*32), triple-buffered 48KB LDS (buf vt%3:
// z 8KB | B 8KB), vmcnt(4)-gated single barrier per vt, XOR swizzle
// (pre-swizzled global source, linear gload_lds dest, swizzled ds_read),
// compiler-scheduled interior (no manual lgkmcnt pins), per-head relu
// fold into oacc. Same FIFO proof as R17: 4 loads/vt -> vmcnt(4) at
// gate(vt) retires exactly vt's; stage(vt+2) targets buf holding dead
// tile vt-1 (WAR-safe: its reads retired before each wave passed
// gate(vt)'s barrier). z re-staged per head (L2-resident, cheap).
// Accumulation order per head unchanged vs R9 core -> identical output.
// Atomics kept (34MB RMW spread over channels ~ plain-store cost) to
// preserve 2-blocks/CU occupancy.
// ---------------------------------------------------------------------------
__global__ __launch_bounds__(256, 2) void gemm_zwk(
    const __hip_bfloat16* __restrict__ z,
    const __hip_bfloat16* __restrict__ WkT,
    const float* __restrict__ bk,
    float* __restrict__ out)
{
  __shared__ __align__(16) char lds[49152];  // 3 bufs x (z 8KB | B 8KB)
  const int tid  = threadIdx.x;              // 0..255
  const int lane = tid & 63;
  const int wave = tid >> 6;                 // 0..3
  const int bn = blockIdx.x, bm = blockIdx.y, hg = blockIdx.z;
  const int wr = wave >> 1, wc = wave & 1;
  const int fr = lane & 15, fq = lane >> 4;

  // staging: dest chunk bytes d0 = tid*16, d1 = 4096 + tid*16 within an
  // 8KB half-buf (128 rows x 64B); source = dest ^ ((dest>>9)&1)<<5.
  int s0 = tid * 16;         s0 ^= ((s0 >> 9) & 1) << 5;
  int s1 = 4096 + tid * 16;  s1 ^= ((s1 >> 9) & 1) << 5;
  const int r0 = s0 >> 6, c0 = (s0 & 63) >> 1;   // row, K-elem
  const int r1 = s1 >> 6, c1 = (s1 & 63) >> 1;

  // fragment read bases (swizzled); row = {wr|wc}*64 + i*16 + fr -> bit3 = fr bit3
  const int fl = ((fr >> 3) & 1) << 5;
  const int baseA = (((wr * 64 + fr) * 64) + fq * 16) ^ fl;
  const int baseB = (((wc * 64 + fr) * 64) + fq * 16) ^ fl;

  const __hip_bfloat16* zb = z + (size_t)(bm * 128) * CC;

  // vt -> head = hg*4 + (vt>>4), kt = (vt&15)*32
#define STAGE_VT(vt, buf) do {                                               \
    const int h_ = hg * 4 + ((vt) >> 4);                                     \
    const int k_ = ((vt) & 15) * 32;                                         \
    const __hip_bfloat16* Bp_ = WkT + (size_t)(h_ * 512 + bn * 128) * CC;    \
    gload_lds16(zb  + (size_t)r0 * CC + k_ + c0, lds + (buf) * 16384 + tid * 16);        \
    gload_lds16(zb  + (size_t)r1 * CC + k_ + c1, lds + (buf) * 16384 + 4096 + tid * 16); \
    gload_lds16(Bp_ + (size_t)r0 * CC + k_ + c0, lds + (buf) * 16384 + 8192 + tid * 16); \
    gload_lds16(Bp_ + (size_t)r1 * CC + k_ + c1, lds + (buf) * 16384 + 12288 + tid * 16);\
  } while (0)

  f32x4 oacc[4][4] = {};

  // prologue: vt 0 -> buf0, vt 1 -> buf1
  STAGE_VT(0, 0);
  STAGE_VT(1, 1);

#pragma unroll
  for (int hh = 0; hh < 4; ++hh) {
    f32x4 acc[4][4] = {};
#pragma unroll
    for (int k2 = 0; k2 < 16; ++k2) {
      const int vt = hh * 16 + k2;
      const int buf = vt % 3;
      const char* Abuf = lds + buf * 16384;
      const char* Bbuf = lds + buf * 16384 + 8192;

      // gate tile vt for all waves
      if (vt == 63) asm volatile("s_waitcnt vmcnt(0)" ::: "memory");
      else          asm volatile("s_waitcnt vmcnt(4)" ::: "memory");
      __builtin_amdgcn_s_barrier();
      __builtin_amdgcn_sched_barrier(0);

      short8 af[4], bf[4];
#pragma unroll
      for (int i = 0; i < 4; ++i) {
        af[i] = *(const short8*)(Abuf + baseA + i * 1024);
        bf[i] = *(const short8*)(Bbuf + baseB + i * 1024);
      }
      if (vt < 62) STAGE_VT(vt + 2, (vt + 2) % 3);

#pragma unroll
      for (int i = 0; i < 4; ++i)
#pragma unroll
        for (int j = 0; j < 4; ++j)
          acc[i][j] = mfma16(af[i], bf[j], acc[i][j]);
    }

    // per-head relu fold
    const int head = hg * 4 + hh;
#pragma unroll
    for (int j = 0; j < 4; ++j) {
      const int d = bn * 128 + wc * 64 + j * 16 + fr;
      const float bias = bk[head * CC + d];
#pragma unroll
      for (int i = 0; i < 4; ++i)
#pragma unroll
        for (int t = 0; t < 4; ++t)
          oacc[i][j][t] += fmaxf(acc[i][j][t] + bias, 0.f);
    }
  }
#undef STAGE_VT

#pragma unroll
  for (int i = 0; i < 4; ++i)
#pragma unroll
    for (int j = 0; j < 4; ++j) {
      const int rbase = bm * 128 + wr * 64 + i * 16 + fq * 4;
      const int d     = bn * 128 + wc * 64 + j * 16 + fr;
#pragma unroll
      for (int t = 0; t < 4; ++t)
        atomicAdd(out + (size_t)(rbase + t) * CC + d, 0.125f * oacc[i][j][t]);
    }
}

// ---------------------------------------------------------------------------
// Merged prep (one launch, block-aligned ranges):
//   [0, 4194304)          x -> bf16 hi+lo split
//   [4194304, 4718592)    WT[j][c] = (j<512?Wth:Wph)[c][j&511], hi+lo
//   [4718592, 6815744)    WkT[j][c] = W_k[j>>9][c][j&511], bf16
//   [6815744, 6816768)    biasqk
//   [6816768, 7865344)    out zero-init (float4 per thread; atomics target)
// ---------------------------------------------------------------------------
__global__ void prep_all(const float* __restrict__ x,
                         const float* __restrict__ Wth, const float* __restrict__ Wph,
                         const float* __restrict__ bt, const float* __restrict__ bp,
                         const float* __restrict__ Wk,
                         __hip_bfloat16* __restrict__ xhi, __hip_bfloat16* __restrict__ xlo,
                         __hip_bfloat16* __restrict__ wthi, __hip_bfloat16* __restrict__ wtlo,
                         __hip_bfloat16* __restrict__ wkt, float* __restrict__ biasqk,
                         float* __restrict__ outz) {
  int idx = blockIdx.x * 256 + threadIdx.x;
  if (idx < 4194304) {
    float v = x[idx];
    __hip_bfloat16 h = __float2bfloat16(v);
    xhi[idx] = h;
    xlo[idx] = __float2bfloat16(v - __bfloat162float(h));
  } else if (idx < 4718592) {
    int i = idx - 4194304;
    int j = i >> 9, c = i & 511;
    const float* W = (j < 512) ? Wth : Wph;
    float v = W[(size_t)c * 512 + (j & 511)];
    __hip_bfloat16 h = __float2bfloat16(v);
    wthi[i] = h;
    wtlo[i] = __float2bfloat16(v - __bfloat162float(h));
  } else if (idx < 6815744) {
    int i = idx - 4718592;
    int j = i >> 9, c = i & 511;
    float v = Wk[(size_t)(j >> 9) * 262144 + (size_t)c * 512 + (j & 511)];
    wkt[i] = __float2bfloat16(v);
  } else if (idx < 6816768) {
    int i = idx - 6815744;
    biasqk[i] = (i < 512) ? bt[i] : bp[i - 512];
  } else if (idx < 7865344) {
    int i = idx - 6816768;
    ((float4*)outz)[i] = make_float4(0.f, 0.f, 0.f, 0.f);
  }
}

extern "C" void kernel_launch(void* const* d_in, const int* in_sizes, int n_in,
                              void* d_out, int out_size, void* d_ws, size_t ws_size,
                              hipStream_t stream) {
  const float* x  = (const float*)d_in[0];
  const float* Wt = (const float*)d_in[1];
  const float* bt = (const float*)d_in[2];
  const float* Wp = (const float*)d_in[3];
  const float* bp = (const float*)d_in[4];
  const float* Wk = (const float*)d_in[5];
  const float* bk = (const float*)d_in[6];
  float* out = (float*)d_out;

  // ---- workspace layout, peak ~100 MiB ----
  const size_t MB = 1024 * 1024;
  char* w = (char*)d_ws;
  __hip_bfloat16* xhi  = (__hip_bfloat16*)(w + 0 * MB);    // 8 MiB
  __hip_bfloat16* xlo  = (__hip_bfloat16*)(w + 8 * MB);    // 8 MiB
  __hip_bfloat16* WThi = (__hip_bfloat16*)(w + 16 * MB);   // 1 MiB
  __hip_bfloat16* WTlo = (__hip_bfloat16*)(w + 17 * MB);   // 1 MiB
  float*          biasqk = (float*)(w + 18 * MB);          // 4 KiB
  __hip_bfloat16* WkT  = (__hip_bfloat16*)(w + 20 * MB);   // 4 MiB
  __hip_bfloat16* QKhi = (__hip_bfloat16*)(w + 24 * MB);   // 16 MiB
  __hip_bfloat16* QKlo = (__hip_bfloat16*)(w + 40 * MB);   // 16 MiB
  __hip_bfloat16* z    = (__hip_bfloat16*)(w + 56 * MB);   // 8 MiB
  float*          segMax = (float*)(w + 64 * MB);          // 4 MiB
  unsigned char*  sim4   = (unsigned char*)(w + 68 * MB);  // 32 MiB

  // 1. prep + out zero-init (single launch)
  prep_all<<<7865344 / 256, 256, 0, stream>>>(x, Wt, Wp, bt, bp, Wk,
                                              xhi, xlo, WThi, WTlo, WkT, biasqk,
                                              out);

  // 2. [Q|K] projections, split precision, hi+lo outputs (8192 x 1024)
  gemm_qk<<<dim3(1024 / 128, NN / 128), 256, 0, stream>>>(
      xhi, xlo, CC, WThi, WTlo, CC, CC, QKhi, QKlo, 1024, biasqk);

  // 3. Q @ K^T -> segMax + deficit nibbles (256x256, compiler-scheduled)
  gemm_sim<<<dim3(NN / 256, NN / 256), 512, 0, stream>>>(
      QKhi, 1024, QKhi + 512, 1024, CC, segMax, sim4);

  // 4. fused select (nibble-filtered exact recompute) + z-gather
  select_zgather<<<NN / 4, 256, 0, stream>>>(segMax, sim4, QKhi, QKlo, x, z);

  // 5. out[n][d] += 0.125 * sum_{h in hg} relu(z @ W_k[h] + b_k[h])
  gemm_zwk<<<dim3(CC / 128, NN / 128, 2), 256, 0, stream>>>(z, WkT, bk, out);
}